// Round 13
// baseline (3919.853 us; speedup 1.0000x reference)
//
#include <hip/hip_runtime.h>
#include <math.h>

// N=98304 nodes, D=256, H=512, E=81920 edges, S=4096 seqs, T=5, HG=256, G3=768
// All GEMMs: C = act(A @ W^T + b), W pre-transposed to WT[K][Nout] so staging is linear.

__device__ __forceinline__ void gload16(const float* g, float* l) {
  __builtin_amdgcn_global_load_lds(
      (const __attribute__((address_space(1))) float*)g,
      (__attribute__((address_space(3))) float*)l, 16, 0, 0);
}

// Packed dual-FMA (VOP3P). Half-rate on CDNA4 (f32 peak = 1 fma/lane/cyc) but
// halves VALU issue slots. PK0 broadcasts a.lo, PK1 broadcasts a.hi.
#define PK0(d, w, a) \
  asm("v_pk_fma_f32 %0, %1, %2, %0 op_sel_hi:[1,0,1]" : "+v"(d) : "v"(w), "v"(a))
#define PK1(d, w, a) \
  asm("v_pk_fma_f32 %0, %1, %2, %0 op_sel:[0,1,0] op_sel_hi:[1,1,1]" : "+v"(d) : "v"(w), "v"(a))

// ---------------------------------------------------------------- weight pre-transpose
struct TMat { const float* s; float* d; int r, c; };
struct TArgs { TMat m[14]; };

__global__ __launch_bounds__(256) void transpose_k(TArgs a) {
  TMat mm = a.m[blockIdx.z];
  int bx = blockIdx.x * 32, by = blockIdx.y * 32;
  if (bx >= mm.c || by >= mm.r) return;
  __shared__ float tl[32][33];
  int lx = threadIdx.x & 31, ly = threadIdx.x >> 5;
#pragma unroll
  for (int i = 0; i < 4; ++i)
    tl[ly + 8 * i][lx] = mm.s[(size_t)(by + ly + 8 * i) * mm.c + bx + lx];
  __syncthreads();
#pragma unroll
  for (int i = 0; i < 4; ++i)
    mm.d[(size_t)(bx + ly + 8 * i) * mm.r + by + lx] = tl[lx][ly + 8 * i];
}

// ---------------------------------------------------------------- deg / cand
__global__ __launch_bounds__(256) void deg_k(const int* __restrict__ row, const int* __restrict__ col,
                                             int* ind, int* outd, int* succ, int E) {
  int e = blockIdx.x * 256 + threadIdx.x;
  if (e >= E) return;
  int r = row[e], c = col[e];
  atomicAdd(&outd[r], 1);
  atomicAdd(&ind[c], 1);
  succ[r] = c;
}

__global__ __launch_bounds__(256) void cand_k(const int* __restrict__ ind, const int* __restrict__ outd,
                                              int* clist, int* cnt, int N) {
  int i = blockIdx.x * 256 + threadIdx.x;
  if (i >= N) return;
  if (ind[i] == 1 && outd[i] == 1) {
    int p = atomicAdd(cnt, 1);
    clist[p] = i;
  }
}

// ---------------------------------------------------------------- main GEMM
// BM = 16*MM, BN = 128, BK = 16. 256 threads; micro-tile MM rows x 8 cols.
// Double-buffered LDS (2x16KB, 4 blocks/CU); stage kt+1 before compute of kt.
// K-loop unrolled by buffer PAIR so the LDS buffer index is a compile-time
// literal -> ds_read addresses fold to constant bases + immediate offsets
// (r12: runtime `cur` cost ~120us/dispatch of addressing VALU).
// amdgpu_num_vgpr(128) r9-proven; XCD swizzle r11-proven; pk_fma r12-proven.
template <int MODE, int MM, bool RELU, bool RESID>
__global__ __launch_bounds__(256)
__attribute__((amdgpu_num_vgpr(128))) void gemm_k(
    const float* __restrict__ A, int lda,
    const float* __restrict__ WT, const float* __restrict__ WT2, int ldw,
    const float* __restrict__ bias, const float* __restrict__ bias2,
    float* __restrict__ C, int ldc,
    int M, const int* __restrict__ Mdev, int K,
    const int* __restrict__ idx1, const int* __restrict__ idx2) {
  constexpr int BM = MM * 16;
  constexpr int NCH = MM / 4;  // A-tile chunks (16 rows of 16 floats) per wave
  if (Mdev) M = *Mdev;

  int bx = blockIdx.x, by = blockIdx.y;
  {
    int gx = gridDim.x, gy = gridDim.y;
    if ((gx & 7) == 0 && gy > 1) {
      int lin = by * gx + bx;       // dispatch order (x fastest)
      int grp = lin / (8 * gy);
      int w = lin - grp * 8 * gy;
      bx = grp * 8 + (w & 7);       // row-panel
      by = w >> 3;                  // col-panel: same panel's cols 8 IDs apart
    }
  }
  const int row0 = bx * BM;
  if (row0 >= M) return;
  const int c0 = by * 128;
  const int t = threadIdx.x;
  const int wv = t >> 6, lane = t & 63;
  const int tx = t & 15, ty = t >> 4;

  const float* WTu = WT;
  const float* biasu = bias;
  if (MODE == 3 && row0 >= (M >> 1)) { WTu = WT2; biasu = bias2; }

  __shared__ __align__(16) float As[2][BM * 16];
  __shared__ __align__(16) float Wt[2][16 * 128];

  // A staging sources (per-lane, quad-swizzled on the GLOBAL side, rule #21).
  const float* asrc[NCH];
  const float* asrc2[NCH];
#pragma unroll
  for (int ci = 0; ci < NCH; ++ci) {
    int c = wv * NCH + ci;
    int m = c * 16 + (lane >> 2);
    int qsrc = (lane & 3) ^ ((m >> 3) & 3);
    int r = row0 + m;
    const float* p0;
    if (MODE == 0 || MODE == 3) {
      p0 = A + (size_t)r * lda;
    } else if (MODE == 1) {
      int v = idx1[r];
      p0 = A + (size_t)v * 256;
      asrc2[ci] = A + (size_t)idx2[v] * 256 + qsrc * 4;
    } else {  // MODE 2
      int s = r / 5, tt = r - s * 5;
      int nid = (tt == 0) ? idx1[s] : idx2[s * 4 + tt - 1];
      p0 = A + (size_t)nid * 256;
    }
    asrc[ci] = p0 + qsrc * 4;
  }
  // W staging: Wt[16][128] linear; chunk = 2 rows (1KB) per gload16 group.
  const float* wbase = WTu + (size_t)(wv * 4 + (lane >> 5)) * ldw + c0 + (lane & 31) * 4;

  float2 acc0[MM][2] = {};
  float2 acc1[MM][2] = {};

  auto STAGE = [&](int kt, int b) {
#pragma unroll
    for (int ci = 0; ci < NCH; ++ci) {
      const float* src;
      if (MODE == 1)
        src = (kt >= 16) ? asrc2[ci] + (kt - 16) * 16 : asrc[ci] + kt * 16;
      else
        src = asrc[ci] + kt * 16;
      gload16(src, &As[b][(wv * NCH + ci) * 256]);
    }
#pragma unroll
    for (int ci = 0; ci < 2; ++ci)
      gload16(wbase + (size_t)(kt * 16 + ci * 2) * ldw, &Wt[b][(wv * 2 + ci) * 256]);
  };

// COMPUTE over compile-time buffer index CUR: constant LDS bases, immediate offsets.
#define COMPUTE(CUR)                                                              \
  {                                                                               \
    _Pragma("unroll") for (int k0 = 0; k0 < 4; ++k0) {                            \
      float4 av[MM];                                                              \
      _Pragma("unroll") for (int i = 0; i < MM; ++i) {                            \
        int m = ty * MM + i;                                                      \
        av[i] = *(const float4*)&As[CUR][m * 16 + ((k0 ^ ((m >> 3) & 3)) << 2)];  \
      }                                                                           \
      _Pragma("unroll") for (int kp = 0; kp < 2; ++kp) {                          \
        const float4 w0e = *(const float4*)&Wt[CUR][(k0 * 4 + kp * 2) * 128 + tx * 4];       \
        const float4 w1e = *(const float4*)&Wt[CUR][(k0 * 4 + kp * 2) * 128 + 64 + tx * 4];  \
        const float4 w0o = *(const float4*)&Wt[CUR][(k0 * 4 + kp * 2 + 1) * 128 + tx * 4];   \
        const float4 w1o = *(const float4*)&Wt[CUR][(k0 * 4 + kp * 2 + 1) * 128 + 64 + tx * 4]; \
        const float2* w0ep = (const float2*)&w0e;                                 \
        const float2* w1ep = (const float2*)&w1e;                                 \
        const float2* w0op = (const float2*)&w0o;                                 \
        const float2* w1op = (const float2*)&w1o;                                 \
        _Pragma("unroll") for (int i = 0; i < MM; ++i) {                          \
          const float2 ap = ((const float2*)&av[i])[kp];                          \
          PK0(acc0[i][0], w0ep[0], ap); PK0(acc0[i][1], w0ep[1], ap);             \
          PK0(acc1[i][0], w1ep[0], ap); PK0(acc1[i][1], w1ep[1], ap);             \
          PK1(acc0[i][0], w0op[0], ap); PK1(acc0[i][1], w0op[1], ap);             \
          PK1(acc1[i][0], w1op[0], ap); PK1(acc1[i][1], w1op[1], ap);             \
        }                                                                         \
      }                                                                           \
    }                                                                             \
  }

  const int nkt = K >> 4;  // always even here (16/32/48)
  STAGE(0, 0);
  __syncthreads();  // drains vmcnt(0): buf0 ready
  for (int kt0 = 0;; kt0 += 2) {
    if (kt0 + 1 < nkt) STAGE(kt0 + 1, 1);
    COMPUTE(0);
    __syncthreads();
    if (kt0 + 1 >= nkt) break;
    if (kt0 + 2 < nkt) STAGE(kt0 + 2, 0);
    COMPUTE(1);
    __syncthreads();
    if (kt0 + 2 >= nkt) break;
  }
#undef COMPUTE

  const float4 b0 = *(const float4*)&biasu[c0 + tx * 4];
  const float4 b1 = *(const float4*)&biasu[c0 + 64 + tx * 4];
#pragma unroll
  for (int i = 0; i < MM; ++i) {
    int r = row0 + ty * MM + i;
    if (r < M) {
      float4 o0, o1;
      o0.x = acc0[i][0].x + b0.x; o0.y = acc0[i][0].y + b0.y;
      o0.z = acc0[i][1].x + b0.z; o0.w = acc0[i][1].y + b0.w;
      o1.x = acc1[i][0].x + b1.x; o1.y = acc1[i][0].y + b1.y;
      o1.z = acc1[i][1].x + b1.z; o1.w = acc1[i][1].y + b1.w;
      if (RELU) {
        o0.x = fmaxf(o0.x, 0.f); o0.y = fmaxf(o0.y, 0.f);
        o0.z = fmaxf(o0.z, 0.f); o0.w = fmaxf(o0.w, 0.f);
        o1.x = fmaxf(o1.x, 0.f); o1.y = fmaxf(o1.y, 0.f);
        o1.w = fmaxf(o1.w, 0.f); o1.z = fmaxf(o1.z, 0.f);
      }
      float* cp = C + (size_t)r * ldc + c0 + tx * 4;
      if (RESID) {
        float4 p0v = *(const float4*)cp;
        float4 p1v = *(const float4*)(cp + 64);
        o0.x += p0v.x; o0.y += p0v.y; o0.z += p0v.z; o0.w += p0v.w;
        o1.x += p1v.x; o1.y += p1v.y; o1.z += p1v.z; o1.w += p1v.w;
      }
      *(float4*)cp = o0;
      *(float4*)(cp + 64) = o1;
    }
  }
}

// ---------------------------------------------------------------- LN + scatter (merge epilogue)
__global__ __launch_bounds__(256) void ln_scatter_k(const float* __restrict__ mt,
                                                    const float* __restrict__ g,
                                                    const float* __restrict__ b,
                                                    float* __restrict__ xw,
                                                    const int* __restrict__ clist,
                                                    const int* __restrict__ cnt) {
  int r = blockIdx.x * 4 + (threadIdx.x >> 6);
  if (r >= *cnt) return;
  int lane = threadIdx.x & 63;
  float4 v = *(const float4*)&mt[(size_t)r * 256 + lane * 4];
  float s = v.x + v.y + v.z + v.w;
  for (int m = 1; m < 64; m <<= 1) s += __shfl_xor(s, m);
  float mu = s * (1.f / 256.f);
  float dx = v.x - mu, dy = v.y - mu, dz = v.z - mu, dw = v.w - mu;
  float q = dx * dx + dy * dy + dz * dz + dw * dw;
  for (int m = 1; m < 64; m <<= 1) q += __shfl_xor(q, m);
  float rs = 1.f / sqrtf(q * (1.f / 256.f) + 1e-5f);
  float4 gv = *(const float4*)&g[lane * 4];
  float4 bv = *(const float4*)&b[lane * 4];
  float4 o;
  o.x = dx * rs * gv.x + bv.x;
  o.y = dy * rs * gv.y + bv.y;
  o.z = dz * rs * gv.z + bv.z;
  o.w = dw * rs * gv.w + bv.w;
  *(float4*)&xw[(size_t)clist[r] * 256 + lane * 4] = o;
}

// ---------------------------------------------------------------- GRU gates (float4 vectorized)
__global__ __launch_bounds__(256) void gates1_k(const float* __restrict__ xgf,
                                                const float* __restrict__ xgb,
                                                const float* __restrict__ gh,
                                                float* __restrict__ hfb,
                                                float* __restrict__ h1o, int p) {
  int idx = blockIdx.x * 256 + threadIdx.x;  // over 2*S*64 quads
  int r = idx >> 6, c4 = (idx & 63) * 4;
  int fwd = r < 4096;
  int s = fwd ? r : r - 4096;
  int tt = fwd ? p : 4 - p;
  const float* xp = (fwd ? xgf : xgb) + ((size_t)s * 5 + tt) * 768 + c4;
  const float* gp = gh + (size_t)r * 768 + c4;
  float4 xr = *(const float4*)xp;
  float4 xz = *(const float4*)(xp + 256);
  float4 xn = *(const float4*)(xp + 512);
  float4 hr = *(const float4*)gp;
  float4 hz = *(const float4*)(gp + 256);
  float4 hn = *(const float4*)(gp + 512);
  float4 hv = *(const float4*)&hfb[(size_t)r * 256 + c4];
  float4 o;
  {
    float rr = 1.f / (1.f + expf(-(xr.x + hr.x)));
    float zz = 1.f / (1.f + expf(-(xz.x + hz.x)));
    o.x = (1.f - zz) * tanhf(xn.x + rr * hn.x) + zz * hv.x;
    rr = 1.f / (1.f + expf(-(xr.y + hr.y)));
    zz = 1.f / (1.f + expf(-(xz.y + hz.y)));
    o.y = (1.f - zz) * tanhf(xn.y + rr * hn.y) + zz * hv.y;
    rr = 1.f / (1.f + expf(-(xr.z + hr.z)));
    zz = 1.f / (1.f + expf(-(xz.z + hz.z)));
    o.z = (1.f - zz) * tanhf(xn.z + rr * hn.z) + zz * hv.z;
    rr = 1.f / (1.f + expf(-(xr.w + hr.w)));
    zz = 1.f / (1.f + expf(-(xz.w + hz.w)));
    o.w = (1.f - zz) * tanhf(xn.w + rr * hn.w) + zz * hv.w;
  }
  *(float4*)&hfb[(size_t)r * 256 + c4] = o;
  *(float4*)&h1o[((size_t)s * 5 + tt) * 512 + (fwd ? 0 : 256) + c4] = o;
}

__global__ __launch_bounds__(256) void gates2_k(const float* __restrict__ xg2,
                                                const float* __restrict__ gh,
                                                float* __restrict__ h2, int p,
                                                float* __restrict__ xw,
                                                const int* __restrict__ csrc) {
  int idx = blockIdx.x * 256 + threadIdx.x;  // over S*64 quads
  int s = idx >> 6, c4 = (idx & 63) * 4;
  const float* xp = xg2 + ((size_t)s * 5 + p) * 768 + c4;
  const float* gp = gh + (size_t)s * 768 + c4;
  float4 xr = *(const float4*)xp;
  float4 xz = *(const float4*)(xp + 256);
  float4 xn = *(const float4*)(xp + 512);
  float4 hr = *(const float4*)gp;
  float4 hz = *(const float4*)(gp + 256);
  float4 hn = *(const float4*)(gp + 512);
  float4 hv = *(const float4*)&h2[(size_t)s * 256 + c4];
  float4 o;
  {
    float rr = 1.f / (1.f + expf(-(xr.x + hr.x)));
    float zz = 1.f / (1.f + expf(-(xz.x + hz.x)));
    o.x = (1.f - zz) * tanhf(xn.x + rr * hn.x) + zz * hv.x;
    rr = 1.f / (1.f + expf(-(xr.y + hr.y)));
    zz = 1.f / (1.f + expf(-(xz.y + hz.y)));
    o.y = (1.f - zz) * tanhf(xn.y + rr * hn.y) + zz * hv.y;
    rr = 1.f / (1.f + expf(-(xr.z + hr.z)));
    zz = 1.f / (1.f + expf(-(xz.z + hz.z)));
    o.z = (1.f - zz) * tanhf(xn.z + rr * hn.z) + zz * hv.z;
    rr = 1.f / (1.f + expf(-(xr.w + hr.w)));
    zz = 1.f / (1.f + expf(-(xz.w + hz.w)));
    o.w = (1.f - zz) * tanhf(xn.w + rr * hn.w) + zz * hv.w;
  }
  *(float4*)&h2[(size_t)s * 256 + c4] = o;
  if (xw) {
    float* wp = xw + (size_t)csrc[s] * 256 + c4;
    float4 old = *(const float4*)wp;
    old.x += o.x; old.y += o.y; old.z += o.z; old.w += o.w;
    *(float4*)wp = old;
  }
}

// ---------------------------------------------------------------- top-k machinery
#define NBUCK (1 << 20)

__global__ __launch_bounds__(256) void imp_k(const float* __restrict__ x, unsigned* __restrict__ keys, int N) {
  int r = blockIdx.x * 4 + (threadIdx.x >> 6);
  int lane = threadIdx.x & 63;
  if (r >= N) return;
  const float* xp = x + (size_t)r * 256;
  float s = 0.f;
#pragma unroll
  for (int d = 0; d < 4; ++d) {
    float v = xp[lane + d * 64];
    s += v * v;
  }
  for (int m = 1; m < 64; m <<= 1) s += __shfl_xor(s, m);
  if (lane == 0) keys[r] = __float_as_uint(sqrtf(s));
}

__global__ __launch_bounds__(256) void hist_k(const unsigned* __restrict__ keys, unsigned* hist, int N) {
  int i = blockIdx.x * 256 + threadIdx.x;
  if (i >= N) return;
  atomicAdd(&hist[keys[i] >> 12], 1u);
}

__global__ __launch_bounds__(256) void bsum_k(const unsigned* __restrict__ hist, unsigned* __restrict__ bsum) {
  int b = blockIdx.x, t = threadIdx.x;
  const uint4* hp = (const uint4*)(hist + (size_t)b * 1024);
  uint4 v = hp[t];
  unsigned s = v.x + v.y + v.z + v.w;
  for (int m = 1; m < 64; m <<= 1) s += __shfl_xor(s, m);
  __shared__ unsigned sm[4];
  if ((t & 63) == 0) sm[t >> 6] = s;
  __syncthreads();
  if (t == 0) bsum[b] = sm[0] + sm[1] + sm[2] + sm[3];
}

__global__ __launch_bounds__(1024) void boff_k(const unsigned* __restrict__ bsum, unsigned* __restrict__ boff) {
  __shared__ unsigned sm[1024];
  int t = threadIdx.x;
  unsigned v = bsum[t];
  sm[t] = v;
  __syncthreads();
  for (int off = 1; off < 1024; off <<= 1) {
    unsigned u = (t >= off) ? sm[t - off] : 0u;
    __syncthreads();
    sm[t] += u;
    __syncthreads();
  }
  boff[t] = sm[t] - v;
}

__global__ __launch_bounds__(256) void scanl_k(const unsigned* __restrict__ hist,
                                               const unsigned* __restrict__ boff,
                                               unsigned* __restrict__ prefix,
                                               unsigned* __restrict__ cursor, int N) {
  int b = blockIdx.x, t = threadIdx.x;
  const uint4* hp = (const uint4*)(hist + (size_t)b * 1024);
  uint4 v = hp[t];
  unsigned tsum = v.x + v.y + v.z + v.w;
  __shared__ unsigned sm[256];
  sm[t] = tsum;
  __syncthreads();
  for (int off = 1; off < 256; off <<= 1) {
    unsigned u = (t >= off) ? sm[t - off] : 0u;
    __syncthreads();
    sm[t] += u;
    __syncthreads();
  }
  unsigned e = boff[b] + sm[t] - tsum;
  uint4 o;
  o.x = e;
  o.y = e + v.x;
  o.z = o.y + v.y;
  o.w = o.z + v.z;
  ((uint4*)(prefix + (size_t)b * 1024))[t] = o;
  ((uint4*)(cursor + (size_t)b * 1024))[t] = o;
  if (b == 0 && t == 0) prefix[NBUCK] = (unsigned)N;
}

__global__ __launch_bounds__(256) void scatter_k(const unsigned* __restrict__ keys, unsigned* cursor,
                                                 unsigned* skeys, int* sidx, int N) {
  int i = blockIdx.x * 256 + threadIdx.x;
  if (i >= N) return;
  unsigned k = keys[i];
  unsigned pos = atomicAdd(&cursor[k >> 12], 1u);
  skeys[pos] = k;
  sidx[pos] = i;
}

__global__ __launch_bounds__(256) void rank_k(const unsigned* __restrict__ keys,
                                              const unsigned* __restrict__ prefix,
                                              const unsigned* __restrict__ skeys,
                                              const int* __restrict__ sidx,
                                              int* __restrict__ noo, int* __restrict__ oon,
                                              int N, int KEEP) {
  int i = blockIdx.x * 256 + threadIdx.x;
  if (i >= N) return;
  unsigned k = keys[i];
  unsigned b = k >> 12;
  unsigned lo = prefix[b], hi = prefix[b + 1];
  int cnt = N - (int)hi;
  for (unsigned p = lo; p < hi; ++p) {
    unsigned kj = skeys[p];
    if (kj > k || (kj == k && sidx[p] < i)) ++cnt;
  }
  if (cnt < KEEP) {
    noo[i] = cnt;
    oon[cnt] = i;
  } else {
    noo[i] = -1;
  }
}

__global__ __launch_bounds__(256) void gather_k(const float* __restrict__ x, const int* __restrict__ oon,
                                                float* __restrict__ out, int KEEP) {
  int idx = blockIdx.x * 256 + threadIdx.x;
  if (idx >= KEEP * 64) return;
  int r = idx >> 6, q = idx & 63;
  *(float4*)(out + (size_t)r * 256 + q * 4) =
      *(const float4*)(x + (size_t)oon[r] * 256 + q * 4);
}

__global__ __launch_bounds__(256) void edges_k(const int* __restrict__ row, const int* __restrict__ col,
                                               const int* __restrict__ et, const int* __restrict__ noo,
                                               float* __restrict__ out_ei, float* __restrict__ out_et,
                                               int E) {
  int e = blockIdx.x * 256 + threadIdx.x;
  if (e >= E) return;
  int nr = noo[row[e]], nc = noo[col[e]];
  bool ok = (nr >= 0) && (nc >= 0);
  out_ei[e] = ok ? (float)nr : -1.f;
  out_ei[E + e] = ok ? (float)nc : -1.f;
  out_et[e] = ok ? (float)et[e] : -1.f;
}

// ---------------------------------------------------------------- launch
extern "C" void kernel_launch(void* const* d_in, const int* in_sizes, int n_in,
                              void* d_out, int out_size, void* d_ws, size_t ws_size,
                              hipStream_t stream) {
  const float* x0 = (const float*)d_in[0];
  const int* eidx = (const int*)d_in[1];
  const int* etype = (const int*)d_in[2];
  const int* csrc = (const int*)d_in[3];
  const int* ctgt = (const int*)d_in[4];
  const float* Wm1 = (const float*)d_in[5];
  const float* bm1 = (const float*)d_in[6];
  const float* Wm2 = (const float*)d_in[7];
  const float* bm2 = (const float*)d_in[8];
  const float* lng = (const float*)d_in[9];
  const float* lnb = (const float*)d_in[10];
  const float* aw1 = (const float*)d_in[11];
  const float* ab1 = (const float*)d_in[12];
  const float* aw2 = (const float*)d_in[13];
  const float* ab2 = (const float*)d_in[14];
  const float* g0wih = (const float*)d_in[15];
  const float* g0whh = (const float*)d_in[16];
  const float* g0bih = (const float*)d_in[17];
  const float* g0bhh = (const float*)d_in[18];
  const float* g1wih = (const float*)d_in[19];
  const float* g1whh = (const float*)d_in[20];
  const float* g1bih = (const float*)d_in[21];
  const float* g1bhh = (const float*)d_in[22];

  const int N = in_sizes[0] / 256;  // 98304
  const int E = in_sizes[2];        // 81920
  const int S = in_sizes[3];        // 4096
  const int KEEP = (out_size - 3 * E) / 256;
  const int* erow = eidx;
  const int* ecol = eidx + E;

  // ---- workspace carve ----
  unsigned char* w = (unsigned char*)d_ws;
  size_t off = 0;
  auto carve = [&](size_t bytes) -> void* {
    void* p = w + off;
    off += (bytes + 255) & ~(size_t)255;
    return p;
  };
  float* xw = (float*)carve((size_t)N * 256 * 4);
  float* big = (float*)carve((size_t)N * 512 * 4);
  float* wt = (float*)carve((size_t)2555904 * 4);
  float* gh = (float*)carve((size_t)8192 * 768 * 4);
  float* hfb = (float*)carve((size_t)8192 * 256 * 4);
  float* h2 = (float*)carve((size_t)4096 * 256 * 4);
  int* ind = (int*)carve((size_t)N * 4);
  int* outd = (int*)carve((size_t)N * 4);
  int* succ = (int*)carve((size_t)N * 4);
  int* clist = (int*)carve((size_t)N * 4);
  int* cnt = (int*)carve(256);
  unsigned* keys = (unsigned*)carve((size_t)N * 4);
  unsigned* skeys = (unsigned*)carve((size_t)N * 4);
  int* sidx = (int*)carve((size_t)N * 4);
  int* noo = (int*)carve((size_t)N * 4);
  int* oon = (int*)carve((size_t)N * 4);
  (void)ws_size; (void)n_in;

  // WT arena offsets (floats)
  float* wtWm1 = wt;                  // [512][512]
  float* wtWm2 = wt + 262144;         // [512][256]
  float* wtA1 = wt + 393216;          // 3 x [256][512]
  float* wtA2 = wt + 786432;          // 3 x [512][256]
  float* wtG0fih = wt + 1179648;      // [256][768]
  float* wtG0bih = wt + 1376256;      // [256][768]
  float* wtG0fhh = wt + 1572864;      // [256][768]
  float* wtG0bhh = wt + 1769472;      // [256][768]
  float* wtG1ih = wt + 1966080;       // [512][768]
  float* wtG1hh = wt + 2359296;       // [256][768]

  // big sublayout (phases 1-3)
  float* hbuf = big;                  // [N][512] (merge hidden)
  float* mtmp = big + 16777216;       // [32768][256] during merge only
  float* xgf = big;                   // [20480][768]
  float* xgb = big + 15728640;        // [20480][768]
  float* h1o = big + 31457280;        // [4096][5][512]
  float* xg2 = xgf;                   // layer-2 x-gates (xgf dead by then)
  // big sublayout (phase 4 — big is dead after GRU)
  unsigned* hist = (unsigned*)big;            // [NBUCK]
  unsigned* prefix = (unsigned*)big + NBUCK;  // [NBUCK+1]
  unsigned* cursor = (unsigned*)big + 2 * NBUCK + 4;  // [NBUCK], 16B-aligned
  unsigned* bsum = cursor + NBUCK;            // [1024]
  unsigned* boff = bsum + 1024;               // [1024]

  // ---- phase 0: transpose weights, degrees, cand, x copy ----
  TArgs ta;
  ta.m[0] = {Wm1, wtWm1, 512, 512};
  ta.m[1] = {Wm2, wtWm2, 256, 512};
  for (int l = 0; l < 3; ++l) {
    ta.m[2 + l] = {aw1 + (size_t)l * 131072, wtA1 + (size_t)l * 131072, 512, 256};
    ta.m[5 + l] = {aw2 + (size_t)l * 131072, wtA2 + (size_t)l * 131072, 256, 512};
  }
  ta.m[8] = {g0wih, wtG0fih, 768, 256};
  ta.m[9] = {g0wih + 196608, wtG0bih, 768, 256};
  ta.m[10] = {g0whh, wtG0fhh, 768, 256};
  ta.m[11] = {g0whh + 196608, wtG0bhh, 768, 256};
  ta.m[12] = {g1wih, wtG1ih, 768, 512};
  ta.m[13] = {g1whh, wtG1hh, 768, 256};

  hipMemsetAsync(ind, 0, (size_t)N * 4, stream);
  hipMemsetAsync(outd, 0, (size_t)N * 4, stream);
  hipMemsetAsync(succ, 0, (size_t)N * 4, stream);
  hipMemsetAsync(cnt, 0, 4, stream);
  hipMemsetAsync(hfb, 0, (size_t)8192 * 256 * 4, stream);
  hipMemsetAsync(h2, 0, (size_t)4096 * 256 * 4, stream);
  hipMemcpyAsync(xw, x0, (size_t)N * 256 * 4, hipMemcpyDeviceToDevice, stream);

  transpose_k<<<dim3(16, 24, 14), 256, 0, stream>>>(ta);
  deg_k<<<(E + 255) / 256, 256, 0, stream>>>(erow, ecol, ind, outd, succ, E);
  cand_k<<<(N + 255) / 256, 256, 0, stream>>>(ind, outd, clist, cnt, N);

  // ---- phase 1: merge MLP ----
  gemm_k<1, 8, true, false><<<dim3(N / 128, 4), 256, 0, stream>>>(
      x0, 256, wtWm1, nullptr, 512, bm1, nullptr, hbuf, 512, N, cnt, 512, clist, succ);
  gemm_k<0, 8, false, false><<<dim3(N / 128, 2), 256, 0, stream>>>(
      hbuf, 512, wtWm2, nullptr, 256, bm2, nullptr, mtmp, 256, N, cnt, 512, nullptr, nullptr);
  ln_scatter_k<<<N / 4, 256, 0, stream>>>(mtmp, lng, lnb, xw, clist, cnt);

  // ---- phase 2: 3 residual MLP layers ----
  for (int l = 0; l < 3; ++l) {
    gemm_k<0, 8, true, false><<<dim3(N / 128, 4), 256, 0, stream>>>(
        xw, 256, wtA1 + (size_t)l * 131072, nullptr, 512, ab1 + l * 512, nullptr,
        hbuf, 512, N, nullptr, 256, nullptr, nullptr);
    gemm_k<0, 8, false, true><<<dim3(N / 128, 2), 256, 0, stream>>>(
        hbuf, 512, wtA2 + (size_t)l * 131072, nullptr, 256, ab2 + l * 256, nullptr,
        xw, 256, N, nullptr, 512, nullptr, nullptr);
  }

  // ---- phase 3: BiGRU ----
  const int M1 = S * 5;  // 20480
  gemm_k<2, 8, false, false><<<dim3(M1 / 128, 6), 256, 0, stream>>>(
      xw, 256, wtG0fih, nullptr, 768, g0bih, nullptr, xgf, 768, M1, nullptr, 256, csrc, ctgt);
  gemm_k<2, 8, false, false><<<dim3(M1 / 128, 6), 256, 0, stream>>>(
      xw, 256, wtG0bih, nullptr, 768, g0bih + 768, nullptr, xgb, 768, M1, nullptr, 256, csrc, ctgt);
  for (int p = 0; p < 5; ++p) {
    gemm_k<3, 8, false, false><<<dim3(2 * S / 128, 6), 256, 0, stream>>>(
        hfb, 256, wtG0fhh, wtG0bhh, 768, g0bhh, g0bhh + 768, gh, 768, 2 * S, nullptr, 256,
        nullptr, nullptr);
    gates1_k<<<2 * S / 4, 256, 0, stream>>>(xgf, xgb, gh, hfb, h1o, p);
  }
  gemm_k<0, 8, false, false><<<dim3(M1 / 128, 6), 256, 0, stream>>>(
      h1o, 512, wtG1ih, nullptr, 768, g1bih, nullptr, xg2, 768, M1, nullptr, 512, nullptr, nullptr);
  for (int p = 0; p < 5; ++p) {
    gemm_k<0, 4, false, false><<<dim3(S / 64, 6), 256, 0, stream>>>(
        h2, 256, wtG1hh, nullptr, 768, g1bhh, nullptr, gh, 768, S, nullptr, 256, nullptr, nullptr);
    gates2_k<<<S / 4, 256, 0, stream>>>(xg2, gh, h2, p, (p == 4) ? xw : nullptr, csrc);
  }

  // ---- phase 4: top-k compression (hist/prefix/cursor live in `big`, now dead) ----
  imp_k<<<(N + 3) / 4, 256, 0, stream>>>(xw, keys, N);
  hipMemsetAsync(hist, 0, (size_t)NBUCK * 4, stream);
  hist_k<<<(N + 255) / 256, 256, 0, stream>>>(keys, hist, N);
  bsum_k<<<1024, 256, 0, stream>>>(hist, bsum);
  boff_k<<<1, 1024, 0, stream>>>(bsum, boff);
  scanl_k<<<1024, 256, 0, stream>>>(hist, boff, prefix, cursor, N);
  scatter_k<<<(N + 255) / 256, 256, 0, stream>>>(keys, cursor, skeys, sidx, N);
  rank_k<<<(N + 255) / 256, 256, 0, stream>>>(keys, prefix, skeys, sidx, noo, oon, N, KEEP);

  float* out = (float*)d_out;
  gather_k<<<((size_t)KEEP * 64 + 255) / 256, 256, 0, stream>>>(xw, oon, out, KEEP);
  edges_k<<<(E + 255) / 256, 256, 0, stream>>>(
      erow, ecol, etype, noo, out + (size_t)KEEP * 256, out + (size_t)KEEP * 256 + 2 * (size_t)E, E);
}

// Round 14
// 3420.345 us; speedup vs baseline: 1.1460x; 1.1460x over previous
//
#include <hip/hip_runtime.h>
#include <math.h>

// N=98304 nodes, D=256, H=512, E=81920 edges, S=4096 seqs, T=5, HG=256, G3=768
// All GEMMs: C = act(A @ W^T + b), W pre-transposed to WT[K][Nout] so staging is linear.

__device__ __forceinline__ void gload16(const float* g, float* l) {
  __builtin_amdgcn_global_load_lds(
      (const __attribute__((address_space(1))) float*)g,
      (__attribute__((address_space(3))) float*)l, 16, 0, 0);
}

// Packed dual-FMA (VOP3P). Half-rate on CDNA4 (f32 peak = 1 fma/lane/cyc) but
// halves VALU issue slots. PK0 broadcasts a.lo, PK1 broadcasts a.hi.
// r13 lesson: do NOT pair-unroll the K-loop — code dup under the 128-VGPR cap
// spills the accumulators (WRITE_SIZE 98MB -> 790MB, +120us). Runtime `cur` it is.
#define PK0(d, w, a) \
  asm("v_pk_fma_f32 %0, %1, %2, %0 op_sel_hi:[1,0,1]" : "+v"(d) : "v"(w), "v"(a))
#define PK1(d, w, a) \
  asm("v_pk_fma_f32 %0, %1, %2, %0 op_sel:[0,1,0] op_sel_hi:[1,1,1]" : "+v"(d) : "v"(w), "v"(a))

// ---------------------------------------------------------------- weight pre-transpose
struct TMat { const float* s; float* d; int r, c; };
struct TArgs { TMat m[14]; };

__global__ __launch_bounds__(256) void transpose_k(TArgs a) {
  TMat mm = a.m[blockIdx.z];
  int bx = blockIdx.x * 32, by = blockIdx.y * 32;
  if (bx >= mm.c || by >= mm.r) return;
  __shared__ float tl[32][33];
  int lx = threadIdx.x & 31, ly = threadIdx.x >> 5;
#pragma unroll
  for (int i = 0; i < 4; ++i)
    tl[ly + 8 * i][lx] = mm.s[(size_t)(by + ly + 8 * i) * mm.c + bx + lx];
  __syncthreads();
#pragma unroll
  for (int i = 0; i < 4; ++i)
    mm.d[(size_t)(bx + ly + 8 * i) * mm.r + by + lx] = tl[lx][ly + 8 * i];
}

// ---------------------------------------------------------------- deg / cand
__global__ __launch_bounds__(256) void deg_k(const int* __restrict__ row, const int* __restrict__ col,
                                             int* ind, int* outd, int* succ, int E) {
  int e = blockIdx.x * 256 + threadIdx.x;
  if (e >= E) return;
  int r = row[e], c = col[e];
  atomicAdd(&outd[r], 1);
  atomicAdd(&ind[c], 1);
  succ[r] = c;
}

__global__ __launch_bounds__(256) void cand_k(const int* __restrict__ ind, const int* __restrict__ outd,
                                              int* clist, int* cnt, int N) {
  int i = blockIdx.x * 256 + threadIdx.x;
  if (i >= N) return;
  if (ind[i] == 1 && outd[i] == 1) {
    int p = atomicAdd(cnt, 1);
    clist[p] = i;
  }
}

// ---------------------------------------------------------------- main GEMM
// BM = 16*MM, BN = 128, BK = 16. 256 threads; micro-tile MM rows x 8 cols.
// Double-buffered LDS (2x16KB, 4 blocks/CU); stage kt+1 before compute of kt.
// amdgpu_num_vgpr(128): r9-proven. XCD swizzle: r11-proven (FETCH -40%).
// Inner loop uses v_pk_fma_f32 (2 FMAs/inst) with op_sel broadcast of the
// A-operand halves -> VALU issue halved, zero packing movs, bit-identical.
template <int MODE, int MM, bool RELU, bool RESID>
__global__ __launch_bounds__(256)
__attribute__((amdgpu_num_vgpr(128))) void gemm_k(
    const float* __restrict__ A, int lda,
    const float* __restrict__ WT, const float* __restrict__ WT2, int ldw,
    const float* __restrict__ bias, const float* __restrict__ bias2,
    float* __restrict__ C, int ldc,
    int M, const int* __restrict__ Mdev, int K,
    const int* __restrict__ idx1, const int* __restrict__ idx2) {
  constexpr int BM = MM * 16;
  constexpr int NCH = MM / 4;  // A-tile chunks (16 rows of 16 floats) per wave
  if (Mdev) M = *Mdev;

  int bx = blockIdx.x, by = blockIdx.y;
  {
    int gx = gridDim.x, gy = gridDim.y;
    if ((gx & 7) == 0 && gy > 1) {
      int lin = by * gx + bx;       // dispatch order (x fastest)
      int grp = lin / (8 * gy);
      int w = lin - grp * 8 * gy;
      bx = grp * 8 + (w & 7);       // row-panel
      by = w >> 3;                  // col-panel: same panel's cols 8 IDs apart
    }
  }
  const int row0 = bx * BM;
  if (row0 >= M) return;
  const int c0 = by * 128;
  const int t = threadIdx.x;
  const int wv = t >> 6, lane = t & 63;
  const int tx = t & 15, ty = t >> 4;

  const float* WTu = WT;
  const float* biasu = bias;
  if (MODE == 3 && row0 >= (M >> 1)) { WTu = WT2; biasu = bias2; }

  __shared__ __align__(16) float As[2][BM * 16];
  __shared__ __align__(16) float Wt[2][16 * 128];

  // A staging sources (per-lane, quad-swizzled on the GLOBAL side, rule #21).
  const float* asrc[NCH];
  const float* asrc2[NCH];
#pragma unroll
  for (int ci = 0; ci < NCH; ++ci) {
    int c = wv * NCH + ci;
    int m = c * 16 + (lane >> 2);
    int qsrc = (lane & 3) ^ ((m >> 3) & 3);
    int r = row0 + m;
    const float* p0;
    if (MODE == 0 || MODE == 3) {
      p0 = A + (size_t)r * lda;
    } else if (MODE == 1) {
      int v = idx1[r];
      p0 = A + (size_t)v * 256;
      asrc2[ci] = A + (size_t)idx2[v] * 256 + qsrc * 4;
    } else {  // MODE 2
      int s = r / 5, tt = r - s * 5;
      int nid = (tt == 0) ? idx1[s] : idx2[s * 4 + tt - 1];
      p0 = A + (size_t)nid * 256;
    }
    asrc[ci] = p0 + qsrc * 4;
  }
  // W staging: Wt[16][128] linear; chunk = 2 rows (1KB) per gload16 group.
  const float* wbase = WTu + (size_t)(wv * 4 + (lane >> 5)) * ldw + c0 + (lane & 31) * 4;

  float2 acc0[MM][2] = {};
  float2 acc1[MM][2] = {};

  auto STAGE = [&](int kt, int b) {
#pragma unroll
    for (int ci = 0; ci < NCH; ++ci) {
      const float* src;
      if (MODE == 1)
        src = (kt >= 16) ? asrc2[ci] + (kt - 16) * 16 : asrc[ci] + kt * 16;
      else
        src = asrc[ci] + kt * 16;
      gload16(src, &As[b][(wv * NCH + ci) * 256]);
    }
#pragma unroll
    for (int ci = 0; ci < 2; ++ci)
      gload16(wbase + (size_t)(kt * 16 + ci * 2) * ldw, &Wt[b][(wv * 2 + ci) * 256]);
  };

  const int nkt = K >> 4;
  STAGE(0, 0);
  __syncthreads();  // drains vmcnt(0): buf0 ready
  for (int kt = 0; kt < nkt; ++kt) {
    const int cur = kt & 1;
    if (kt + 1 < nkt) STAGE(kt + 1, cur ^ 1);  // in flight across compute

#pragma unroll
    for (int k0 = 0; k0 < 4; ++k0) {
      float4 av[MM];
#pragma unroll
      for (int i = 0; i < MM; ++i) {
        int m = ty * MM + i;
        av[i] = *(const float4*)&As[cur][m * 16 + ((k0 ^ ((m >> 3) & 3)) << 2)];
      }
#pragma unroll
      for (int kp = 0; kp < 2; ++kp) {  // k-pair: k = k0*4 + kp*2 + {0,1}
        const float4 w0e = *(const float4*)&Wt[cur][(k0 * 4 + kp * 2) * 128 + tx * 4];
        const float4 w1e = *(const float4*)&Wt[cur][(k0 * 4 + kp * 2) * 128 + 64 + tx * 4];
        const float4 w0o = *(const float4*)&Wt[cur][(k0 * 4 + kp * 2 + 1) * 128 + tx * 4];
        const float4 w1o = *(const float4*)&Wt[cur][(k0 * 4 + kp * 2 + 1) * 128 + 64 + tx * 4];
        const float2* w0ep = (const float2*)&w0e;
        const float2* w1ep = (const float2*)&w1e;
        const float2* w0op = (const float2*)&w0o;
        const float2* w1op = (const float2*)&w1o;
#pragma unroll
        for (int i = 0; i < MM; ++i) {
          const float2 ap = ((const float2*)&av[i])[kp];
          // even k first, then odd k -> per-element k order unchanged
          PK0(acc0[i][0], w0ep[0], ap); PK0(acc0[i][1], w0ep[1], ap);
          PK0(acc1[i][0], w1ep[0], ap); PK0(acc1[i][1], w1ep[1], ap);
          PK1(acc0[i][0], w0op[0], ap); PK1(acc0[i][1], w0op[1], ap);
          PK1(acc1[i][0], w1op[0], ap); PK1(acc1[i][1], w1op[1], ap);
        }
      }
    }
    __syncthreads();  // drains kt+1 loads (aged under compute) + kt lds reads
  }

  const float4 b0 = *(const float4*)&biasu[c0 + tx * 4];
  const float4 b1 = *(const float4*)&biasu[c0 + 64 + tx * 4];
#pragma unroll
  for (int i = 0; i < MM; ++i) {
    int r = row0 + ty * MM + i;
    if (r < M) {
      float4 o0, o1;
      o0.x = acc0[i][0].x + b0.x; o0.y = acc0[i][0].y + b0.y;
      o0.z = acc0[i][1].x + b0.z; o0.w = acc0[i][1].y + b0.w;
      o1.x = acc1[i][0].x + b1.x; o1.y = acc1[i][0].y + b1.y;
      o1.z = acc1[i][1].x + b1.z; o1.w = acc1[i][1].y + b1.w;
      if (RELU) {
        o0.x = fmaxf(o0.x, 0.f); o0.y = fmaxf(o0.y, 0.f);
        o0.z = fmaxf(o0.z, 0.f); o0.w = fmaxf(o0.w, 0.f);
        o1.x = fmaxf(o1.x, 0.f); o1.y = fmaxf(o1.y, 0.f);
        o1.z = fmaxf(o1.z, 0.f); o1.w = fmaxf(o1.w, 0.f);
      }
      float* cp = C + (size_t)r * ldc + c0 + tx * 4;
      if (RESID) {
        float4 p0v = *(const float4*)cp;
        float4 p1v = *(const float4*)(cp + 64);
        o0.x += p0v.x; o0.y += p0v.y; o0.z += p0v.z; o0.w += p0v.w;
        o1.x += p1v.x; o1.y += p1v.y; o1.z += p1v.z; o1.w += p1v.w;
      }
      *(float4*)cp = o0;
      *(float4*)(cp + 64) = o1;
    }
  }
}

// ---------------------------------------------------------------- LN + scatter (merge epilogue)
__global__ __launch_bounds__(256) void ln_scatter_k(const float* __restrict__ mt,
                                                    const float* __restrict__ g,
                                                    const float* __restrict__ b,
                                                    float* __restrict__ xw,
                                                    const int* __restrict__ clist,
                                                    const int* __restrict__ cnt) {
  int r = blockIdx.x * 4 + (threadIdx.x >> 6);
  if (r >= *cnt) return;
  int lane = threadIdx.x & 63;
  float4 v = *(const float4*)&mt[(size_t)r * 256 + lane * 4];
  float s = v.x + v.y + v.z + v.w;
  for (int m = 1; m < 64; m <<= 1) s += __shfl_xor(s, m);
  float mu = s * (1.f / 256.f);
  float dx = v.x - mu, dy = v.y - mu, dz = v.z - mu, dw = v.w - mu;
  float q = dx * dx + dy * dy + dz * dz + dw * dw;
  for (int m = 1; m < 64; m <<= 1) q += __shfl_xor(q, m);
  float rs = 1.f / sqrtf(q * (1.f / 256.f) + 1e-5f);
  float4 gv = *(const float4*)&g[lane * 4];
  float4 bv = *(const float4*)&b[lane * 4];
  float4 o;
  o.x = dx * rs * gv.x + bv.x;
  o.y = dy * rs * gv.y + bv.y;
  o.z = dz * rs * gv.z + bv.z;
  o.w = dw * rs * gv.w + bv.w;
  *(float4*)&xw[(size_t)clist[r] * 256 + lane * 4] = o;
}

// ---------------------------------------------------------------- GRU gates (float4 vectorized)
__global__ __launch_bounds__(256) void gates1_k(const float* __restrict__ xgf,
                                                const float* __restrict__ xgb,
                                                const float* __restrict__ gh,
                                                float* __restrict__ hfb,
                                                float* __restrict__ h1o, int p) {
  int idx = blockIdx.x * 256 + threadIdx.x;  // over 2*S*64 quads
  int r = idx >> 6, c4 = (idx & 63) * 4;
  int fwd = r < 4096;
  int s = fwd ? r : r - 4096;
  int tt = fwd ? p : 4 - p;
  const float* xp = (fwd ? xgf : xgb) + ((size_t)s * 5 + tt) * 768 + c4;
  const float* gp = gh + (size_t)r * 768 + c4;
  float4 xr = *(const float4*)xp;
  float4 xz = *(const float4*)(xp + 256);
  float4 xn = *(const float4*)(xp + 512);
  float4 hr = *(const float4*)gp;
  float4 hz = *(const float4*)(gp + 256);
  float4 hn = *(const float4*)(gp + 512);
  float4 hv = *(const float4*)&hfb[(size_t)r * 256 + c4];
  float4 o;
  {
    float rr = 1.f / (1.f + expf(-(xr.x + hr.x)));
    float zz = 1.f / (1.f + expf(-(xz.x + hz.x)));
    o.x = (1.f - zz) * tanhf(xn.x + rr * hn.x) + zz * hv.x;
    rr = 1.f / (1.f + expf(-(xr.y + hr.y)));
    zz = 1.f / (1.f + expf(-(xz.y + hz.y)));
    o.y = (1.f - zz) * tanhf(xn.y + rr * hn.y) + zz * hv.y;
    rr = 1.f / (1.f + expf(-(xr.z + hr.z)));
    zz = 1.f / (1.f + expf(-(xz.z + hz.z)));
    o.z = (1.f - zz) * tanhf(xn.z + rr * hn.z) + zz * hv.z;
    rr = 1.f / (1.f + expf(-(xr.w + hr.w)));
    zz = 1.f / (1.f + expf(-(xz.w + hz.w)));
    o.w = (1.f - zz) * tanhf(xn.w + rr * hn.w) + zz * hv.w;
  }
  *(float4*)&hfb[(size_t)r * 256 + c4] = o;
  *(float4*)&h1o[((size_t)s * 5 + tt) * 512 + (fwd ? 0 : 256) + c4] = o;
}

__global__ __launch_bounds__(256) void gates2_k(const float* __restrict__ xg2,
                                                const float* __restrict__ gh,
                                                float* __restrict__ h2, int p,
                                                float* __restrict__ xw,
                                                const int* __restrict__ csrc) {
  int idx = blockIdx.x * 256 + threadIdx.x;  // over S*64 quads
  int s = idx >> 6, c4 = (idx & 63) * 4;
  const float* xp = xg2 + ((size_t)s * 5 + p) * 768 + c4;
  const float* gp = gh + (size_t)s * 768 + c4;
  float4 xr = *(const float4*)xp;
  float4 xz = *(const float4*)(xp + 256);
  float4 xn = *(const float4*)(xp + 512);
  float4 hr = *(const float4*)gp;
  float4 hz = *(const float4*)(gp + 256);
  float4 hn = *(const float4*)(gp + 512);
  float4 hv = *(const float4*)&h2[(size_t)s * 256 + c4];
  float4 o;
  {
    float rr = 1.f / (1.f + expf(-(xr.x + hr.x)));
    float zz = 1.f / (1.f + expf(-(xz.x + hz.x)));
    o.x = (1.f - zz) * tanhf(xn.x + rr * hn.x) + zz * hv.x;
    rr = 1.f / (1.f + expf(-(xr.y + hr.y)));
    zz = 1.f / (1.f + expf(-(xz.y + hz.y)));
    o.y = (1.f - zz) * tanhf(xn.y + rr * hn.y) + zz * hv.y;
    rr = 1.f / (1.f + expf(-(xr.z + hr.z)));
    zz = 1.f / (1.f + expf(-(xz.z + hz.z)));
    o.z = (1.f - zz) * tanhf(xn.z + rr * hn.z) + zz * hv.z;
    rr = 1.f / (1.f + expf(-(xr.w + hr.w)));
    zz = 1.f / (1.f + expf(-(xz.w + hz.w)));
    o.w = (1.f - zz) * tanhf(xn.w + rr * hn.w) + zz * hv.w;
  }
  *(float4*)&h2[(size_t)s * 256 + c4] = o;
  if (xw) {
    float* wp = xw + (size_t)csrc[s] * 256 + c4;
    float4 old = *(const float4*)wp;
    old.x += o.x; old.y += o.y; old.z += o.z; old.w += o.w;
    *(float4*)wp = old;
  }
}

// ---------------------------------------------------------------- top-k machinery
#define NBUCK (1 << 20)

__global__ __launch_bounds__(256) void imp_k(const float* __restrict__ x, unsigned* __restrict__ keys, int N) {
  int r = blockIdx.x * 4 + (threadIdx.x >> 6);
  int lane = threadIdx.x & 63;
  if (r >= N) return;
  const float* xp = x + (size_t)r * 256;
  float s = 0.f;
#pragma unroll
  for (int d = 0; d < 4; ++d) {
    float v = xp[lane + d * 64];
    s += v * v;
  }
  for (int m = 1; m < 64; m <<= 1) s += __shfl_xor(s, m);
  if (lane == 0) keys[r] = __float_as_uint(sqrtf(s));
}

__global__ __launch_bounds__(256) void hist_k(const unsigned* __restrict__ keys, unsigned* hist, int N) {
  int i = blockIdx.x * 256 + threadIdx.x;
  if (i >= N) return;
  atomicAdd(&hist[keys[i] >> 12], 1u);
}

__global__ __launch_bounds__(256) void bsum_k(const unsigned* __restrict__ hist, unsigned* __restrict__ bsum) {
  int b = blockIdx.x, t = threadIdx.x;
  const uint4* hp = (const uint4*)(hist + (size_t)b * 1024);
  uint4 v = hp[t];
  unsigned s = v.x + v.y + v.z + v.w;
  for (int m = 1; m < 64; m <<= 1) s += __shfl_xor(s, m);
  __shared__ unsigned sm[4];
  if ((t & 63) == 0) sm[t >> 6] = s;
  __syncthreads();
  if (t == 0) bsum[b] = sm[0] + sm[1] + sm[2] + sm[3];
}

__global__ __launch_bounds__(1024) void boff_k(const unsigned* __restrict__ bsum, unsigned* __restrict__ boff) {
  __shared__ unsigned sm[1024];
  int t = threadIdx.x;
  unsigned v = bsum[t];
  sm[t] = v;
  __syncthreads();
  for (int off = 1; off < 1024; off <<= 1) {
    unsigned u = (t >= off) ? sm[t - off] : 0u;
    __syncthreads();
    sm[t] += u;
    __syncthreads();
  }
  boff[t] = sm[t] - v;
}

__global__ __launch_bounds__(256) void scanl_k(const unsigned* __restrict__ hist,
                                               const unsigned* __restrict__ boff,
                                               unsigned* __restrict__ prefix,
                                               unsigned* __restrict__ cursor, int N) {
  int b = blockIdx.x, t = threadIdx.x;
  const uint4* hp = (const uint4*)(hist + (size_t)b * 1024);
  uint4 v = hp[t];
  unsigned tsum = v.x + v.y + v.z + v.w;
  __shared__ unsigned sm[256];
  sm[t] = tsum;
  __syncthreads();
  for (int off = 1; off < 256; off <<= 1) {
    unsigned u = (t >= off) ? sm[t - off] : 0u;
    __syncthreads();
    sm[t] += u;
    __syncthreads();
  }
  unsigned e = boff[b] + sm[t] - tsum;
  uint4 o;
  o.x = e;
  o.y = e + v.x;
  o.z = o.y + v.y;
  o.w = o.z + v.z;
  ((uint4*)(prefix + (size_t)b * 1024))[t] = o;
  ((uint4*)(cursor + (size_t)b * 1024))[t] = o;
  if (b == 0 && t == 0) prefix[NBUCK] = (unsigned)N;
}

__global__ __launch_bounds__(256) void scatter_k(const unsigned* __restrict__ keys, unsigned* cursor,
                                                 unsigned* skeys, int* sidx, int N) {
  int i = blockIdx.x * 256 + threadIdx.x;
  if (i >= N) return;
  unsigned k = keys[i];
  unsigned pos = atomicAdd(&cursor[k >> 12], 1u);
  skeys[pos] = k;
  sidx[pos] = i;
}

__global__ __launch_bounds__(256) void rank_k(const unsigned* __restrict__ keys,
                                              const unsigned* __restrict__ prefix,
                                              const unsigned* __restrict__ skeys,
                                              const int* __restrict__ sidx,
                                              int* __restrict__ noo, int* __restrict__ oon,
                                              int N, int KEEP) {
  int i = blockIdx.x * 256 + threadIdx.x;
  if (i >= N) return;
  unsigned k = keys[i];
  unsigned b = k >> 12;
  unsigned lo = prefix[b], hi = prefix[b + 1];
  int cnt = N - (int)hi;
  for (unsigned p = lo; p < hi; ++p) {
    unsigned kj = skeys[p];
    if (kj > k || (kj == k && sidx[p] < i)) ++cnt;
  }
  if (cnt < KEEP) {
    noo[i] = cnt;
    oon[cnt] = i;
  } else {
    noo[i] = -1;
  }
}

__global__ __launch_bounds__(256) void gather_k(const float* __restrict__ x, const int* __restrict__ oon,
                                                float* __restrict__ out, int KEEP) {
  int idx = blockIdx.x * 256 + threadIdx.x;
  if (idx >= KEEP * 64) return;
  int r = idx >> 6, q = idx & 63;
  *(float4*)(out + (size_t)r * 256 + q * 4) =
      *(const float4*)(x + (size_t)oon[r] * 256 + q * 4);
}

__global__ __launch_bounds__(256) void edges_k(const int* __restrict__ row, const int* __restrict__ col,
                                               const int* __restrict__ et, const int* __restrict__ noo,
                                               float* __restrict__ out_ei, float* __restrict__ out_et,
                                               int E) {
  int e = blockIdx.x * 256 + threadIdx.x;
  if (e >= E) return;
  int nr = noo[row[e]], nc = noo[col[e]];
  bool ok = (nr >= 0) && (nc >= 0);
  out_ei[e] = ok ? (float)nr : -1.f;
  out_ei[E + e] = ok ? (float)nc : -1.f;
  out_et[e] = ok ? (float)et[e] : -1.f;
}

// ---------------------------------------------------------------- launch
extern "C" void kernel_launch(void* const* d_in, const int* in_sizes, int n_in,
                              void* d_out, int out_size, void* d_ws, size_t ws_size,
                              hipStream_t stream) {
  const float* x0 = (const float*)d_in[0];
  const int* eidx = (const int*)d_in[1];
  const int* etype = (const int*)d_in[2];
  const int* csrc = (const int*)d_in[3];
  const int* ctgt = (const int*)d_in[4];
  const float* Wm1 = (const float*)d_in[5];
  const float* bm1 = (const float*)d_in[6];
  const float* Wm2 = (const float*)d_in[7];
  const float* bm2 = (const float*)d_in[8];
  const float* lng = (const float*)d_in[9];
  const float* lnb = (const float*)d_in[10];
  const float* aw1 = (const float*)d_in[11];
  const float* ab1 = (const float*)d_in[12];
  const float* aw2 = (const float*)d_in[13];
  const float* ab2 = (const float*)d_in[14];
  const float* g0wih = (const float*)d_in[15];
  const float* g0whh = (const float*)d_in[16];
  const float* g0bih = (const float*)d_in[17];
  const float* g0bhh = (const float*)d_in[18];
  const float* g1wih = (const float*)d_in[19];
  const float* g1whh = (const float*)d_in[20];
  const float* g1bih = (const float*)d_in[21];
  const float* g1bhh = (const float*)d_in[22];

  const int N = in_sizes[0] / 256;  // 98304
  const int E = in_sizes[2];        // 81920
  const int S = in_sizes[3];        // 4096
  const int KEEP = (out_size - 3 * E) / 256;
  const int* erow = eidx;
  const int* ecol = eidx + E;

  // ---- workspace carve ----
  unsigned char* w = (unsigned char*)d_ws;
  size_t off = 0;
  auto carve = [&](size_t bytes) -> void* {
    void* p = w + off;
    off += (bytes + 255) & ~(size_t)255;
    return p;
  };
  float* xw = (float*)carve((size_t)N * 256 * 4);
  float* big = (float*)carve((size_t)N * 512 * 4);
  float* wt = (float*)carve((size_t)2555904 * 4);
  float* gh = (float*)carve((size_t)8192 * 768 * 4);
  float* hfb = (float*)carve((size_t)8192 * 256 * 4);
  float* h2 = (float*)carve((size_t)4096 * 256 * 4);
  int* ind = (int*)carve((size_t)N * 4);
  int* outd = (int*)carve((size_t)N * 4);
  int* succ = (int*)carve((size_t)N * 4);
  int* clist = (int*)carve((size_t)N * 4);
  int* cnt = (int*)carve(256);
  unsigned* keys = (unsigned*)carve((size_t)N * 4);
  unsigned* skeys = (unsigned*)carve((size_t)N * 4);
  int* sidx = (int*)carve((size_t)N * 4);
  int* noo = (int*)carve((size_t)N * 4);
  int* oon = (int*)carve((size_t)N * 4);
  (void)ws_size; (void)n_in;

  // WT arena offsets (floats)
  float* wtWm1 = wt;                  // [512][512]
  float* wtWm2 = wt + 262144;         // [512][256]
  float* wtA1 = wt + 393216;          // 3 x [256][512]
  float* wtA2 = wt + 786432;          // 3 x [512][256]
  float* wtG0fih = wt + 1179648;      // [256][768]
  float* wtG0bih = wt + 1376256;      // [256][768]
  float* wtG0fhh = wt + 1572864;      // [256][768]
  float* wtG0bhh = wt + 1769472;      // [256][768]
  float* wtG1ih = wt + 1966080;       // [512][768]
  float* wtG1hh = wt + 2359296;       // [256][768]

  // big sublayout (phases 1-3)
  float* hbuf = big;                  // [N][512] (merge hidden)
  float* mtmp = big + 16777216;       // [32768][256] during merge only
  float* xgf = big;                   // [20480][768]
  float* xgb = big + 15728640;        // [20480][768]
  float* h1o = big + 31457280;        // [4096][5][512]
  float* xg2 = xgf;                   // layer-2 x-gates (xgf dead by then)
  // big sublayout (phase 4 — big is dead after GRU)
  unsigned* hist = (unsigned*)big;            // [NBUCK]
  unsigned* prefix = (unsigned*)big + NBUCK;  // [NBUCK+1]
  unsigned* cursor = (unsigned*)big + 2 * NBUCK + 4;  // [NBUCK], 16B-aligned
  unsigned* bsum = cursor + NBUCK;            // [1024]
  unsigned* boff = bsum + 1024;               // [1024]

  // ---- phase 0: transpose weights, degrees, cand, x copy ----
  TArgs ta;
  ta.m[0] = {Wm1, wtWm1, 512, 512};
  ta.m[1] = {Wm2, wtWm2, 256, 512};
  for (int l = 0; l < 3; ++l) {
    ta.m[2 + l] = {aw1 + (size_t)l * 131072, wtA1 + (size_t)l * 131072, 512, 256};
    ta.m[5 + l] = {aw2 + (size_t)l * 131072, wtA2 + (size_t)l * 131072, 256, 512};
  }
  ta.m[8] = {g0wih, wtG0fih, 768, 256};
  ta.m[9] = {g0wih + 196608, wtG0bih, 768, 256};
  ta.m[10] = {g0whh, wtG0fhh, 768, 256};
  ta.m[11] = {g0whh + 196608, wtG0bhh, 768, 256};
  ta.m[12] = {g1wih, wtG1ih, 768, 512};
  ta.m[13] = {g1whh, wtG1hh, 768, 256};

  hipMemsetAsync(ind, 0, (size_t)N * 4, stream);
  hipMemsetAsync(outd, 0, (size_t)N * 4, stream);
  hipMemsetAsync(succ, 0, (size_t)N * 4, stream);
  hipMemsetAsync(cnt, 0, 4, stream);
  hipMemsetAsync(hfb, 0, (size_t)8192 * 256 * 4, stream);
  hipMemsetAsync(h2, 0, (size_t)4096 * 256 * 4, stream);
  hipMemcpyAsync(xw, x0, (size_t)N * 256 * 4, hipMemcpyDeviceToDevice, stream);

  transpose_k<<<dim3(16, 24, 14), 256, 0, stream>>>(ta);
  deg_k<<<(E + 255) / 256, 256, 0, stream>>>(erow, ecol, ind, outd, succ, E);
  cand_k<<<(N + 255) / 256, 256, 0, stream>>>(ind, outd, clist, cnt, N);

  // ---- phase 1: merge MLP ----
  gemm_k<1, 8, true, false><<<dim3(N / 128, 4), 256, 0, stream>>>(
      x0, 256, wtWm1, nullptr, 512, bm1, nullptr, hbuf, 512, N, cnt, 512, clist, succ);
  gemm_k<0, 8, false, false><<<dim3(N / 128, 2), 256, 0, stream>>>(
      hbuf, 512, wtWm2, nullptr, 256, bm2, nullptr, mtmp, 256, N, cnt, 512, nullptr, nullptr);
  ln_scatter_k<<<N / 4, 256, 0, stream>>>(mtmp, lng, lnb, xw, clist, cnt);

  // ---- phase 2: 3 residual MLP layers ----
  for (int l = 0; l < 3; ++l) {
    gemm_k<0, 8, true, false><<<dim3(N / 128, 4), 256, 0, stream>>>(
        xw, 256, wtA1 + (size_t)l * 131072, nullptr, 512, ab1 + l * 512, nullptr,
        hbuf, 512, N, nullptr, 256, nullptr, nullptr);
    gemm_k<0, 8, false, true><<<dim3(N / 128, 2), 256, 0, stream>>>(
        hbuf, 512, wtA2 + (size_t)l * 131072, nullptr, 256, ab2 + l * 256, nullptr,
        xw, 256, N, nullptr, 512, nullptr, nullptr);
  }

  // ---- phase 3: BiGRU ----
  const int M1 = S * 5;  // 20480
  gemm_k<2, 8, false, false><<<dim3(M1 / 128, 6), 256, 0, stream>>>(
      xw, 256, wtG0fih, nullptr, 768, g0bih, nullptr, xgf, 768, M1, nullptr, 256, csrc, ctgt);
  gemm_k<2, 8, false, false><<<dim3(M1 / 128, 6), 256, 0, stream>>>(
      xw, 256, wtG0bih, nullptr, 768, g0bih + 768, nullptr, xgb, 768, M1, nullptr, 256, csrc, ctgt);
  for (int p = 0; p < 5; ++p) {
    gemm_k<3, 8, false, false><<<dim3(2 * S / 128, 6), 256, 0, stream>>>(
        hfb, 256, wtG0fhh, wtG0bhh, 768, g0bhh, g0bhh + 768, gh, 768, 2 * S, nullptr, 256,
        nullptr, nullptr);
    gates1_k<<<2 * S / 4, 256, 0, stream>>>(xgf, xgb, gh, hfb, h1o, p);
  }
  gemm_k<0, 8, false, false><<<dim3(M1 / 128, 6), 256, 0, stream>>>(
      h1o, 512, wtG1ih, nullptr, 768, g1bih, nullptr, xg2, 768, M1, nullptr, 512, nullptr, nullptr);
  for (int p = 0; p < 5; ++p) {
    gemm_k<0, 4, false, false><<<dim3(S / 64, 6), 256, 0, stream>>>(
        h2, 256, wtG1hh, nullptr, 768, g1bhh, nullptr, gh, 768, S, nullptr, 256, nullptr, nullptr);
    gates2_k<<<S / 4, 256, 0, stream>>>(xg2, gh, h2, p, (p == 4) ? xw : nullptr, csrc);
  }

  // ---- phase 4: top-k compression (hist/prefix/cursor live in `big`, now dead) ----
  imp_k<<<(N + 3) / 4, 256, 0, stream>>>(xw, keys, N);
  hipMemsetAsync(hist, 0, (size_t)NBUCK * 4, stream);
  hist_k<<<(N + 255) / 256, 256, 0, stream>>>(keys, hist, N);
  bsum_k<<<1024, 256, 0, stream>>>(hist, bsum);
  boff_k<<<1, 1024, 0, stream>>>(bsum, boff);
  scanl_k<<<1024, 256, 0, stream>>>(hist, boff, prefix, cursor, N);
  scatter_k<<<(N + 255) / 256, 256, 0, stream>>>(keys, cursor, skeys, sidx, N);
  rank_k<<<(N + 255) / 256, 256, 0, stream>>>(keys, prefix, skeys, sidx, noo, oon, N, KEEP);

  float* out = (float*)d_out;
  gather_k<<<((size_t)KEEP * 64 + 255) / 256, 256, 0, stream>>>(xw, oon, out, KEEP);
  edges_k<<<(E + 255) / 256, 256, 0, stream>>>(
      erow, ecol, etype, noo, out + (size_t)KEEP * 256, out + (size_t)KEEP * 256 + 2 * (size_t)E, E);
}